// Round 7
// baseline (1648.947 us; speedup 1.0000x reference)
//
#include <hip/hip_runtime.h>

typedef unsigned short u16;
typedef unsigned int   u32;
typedef short s16x8 __attribute__((ext_vector_type(8)));
typedef float f32x4 __attribute__((ext_vector_type(4)));

#define MFMA16(A,B,C) __builtin_amdgcn_mfma_f32_16x16x32_bf16((A),(B),(C),0,0,0)
#define BAR()  asm volatile("s_barrier" ::: "memory")
#define VMC4   asm volatile("s_waitcnt vmcnt(4)" ::: "memory")
#define VMC0   asm volatile("s_waitcnt vmcnt(0)" ::: "memory")

#define B_   32
#define S_   257
#define E_   1024
#define H_   16
#define D_   64
#define I_   4096
#define M_   (B_*S_)   // 8224
#define MT_  33        // ceil(M/256)

__device__ __forceinline__ u16 f2bf(float f) {
    u32 u = __float_as_uint(f);
    u32 r = u + 0x7fffu + ((u >> 16) & 1u);
    return (u16)(r >> 16);
}
__device__ __forceinline__ float bf2f(u16 b) {
    return __uint_as_float(((u32)b) << 16);
}

__device__ __forceinline__ void gload16(const void* g, void* l) {
    __builtin_amdgcn_global_load_lds(
        (const __attribute__((address_space(1))) u32*)g,
        (__attribute__((address_space(3))) u32*)l, 16, 0, 0);
}

// ---------------- weight fp32 -> bf16 convert (12M elems) ----------------
__global__ __launch_bounds__(256)
void convert_w_kernel(const float* __restrict__ qw, const float* __restrict__ kw,
                      const float* __restrict__ vw, const float* __restrict__ ow,
                      const float* __restrict__ f1, const float* __restrict__ f2,
                      u16* __restrict__ dst)
{
    const int total4 = (12 * 1048576) / 4;
    for (int i = blockIdx.x * 256 + threadIdx.x; i < total4; i += gridDim.x * 256) {
        int e = i * 4;
        int seg = e >> 20;
        const float* srcp; int off;
        if (seg < 4)      { srcp = (seg == 0 ? qw : seg == 1 ? kw : seg == 2 ? vw : ow); off = e & 1048575; }
        else if (seg < 8) { srcp = f1; off = e - 4 * 1048576; }
        else              { srcp = f2; off = e - 8 * 1048576; }
        float4 v = *(const float4*)(srcp + off);
        ushort4 o;
        o.x = f2bf(v.x); o.y = f2bf(v.y); o.z = f2bf(v.z); o.w = f2bf(v.w);
        *(ushort4*)(dst + e) = o;
    }
}

// ---------------- combined mask table: msum[b][sq][272] bf16 ----------------
__global__ __launch_bounds__(256)
void mask_combine_kernel(const float* __restrict__ am, const float* __restrict__ cm,
                         u16* __restrict__ msum)
{
    const int total = B_ * S_ * 272;
    for (int i = blockIdx.x * 256 + threadIdx.x; i < total; i += gridDim.x * 256) {
        int skv = i % 272;
        int rem = i / 272;
        int sq  = rem % S_;
        int b   = rem / S_;
        float v;
        if (skv < S_) {
            size_t o = ((size_t)b * S_ + sq) * S_ + skv;
            v = am[o] + cm[o];
        } else v = -1e30f;
        msum[i] = f2bf(v);
    }
}

// ---------------- LayerNorm row kernel ----------------
__global__ __launch_bounds__(256)
void ln_kernel(const float* __restrict__ src, const float* __restrict__ gam,
               const float* __restrict__ bet, u16* __restrict__ dst)
{
    int row = blockIdx.x;
    const float4* p = (const float4*)(src + (size_t)row * E_);
    float4 x = p[threadIdx.x];
    float s  = x.x + x.y + x.z + x.w;
    float s2 = x.x * x.x + x.y * x.y + x.z * x.z + x.w * x.w;
#pragma unroll
    for (int xm = 1; xm < 64; xm <<= 1) {
        s  += __shfl_xor(s,  xm, 64);
        s2 += __shfl_xor(s2, xm, 64);
    }
    __shared__ float red[8];
    int wv = threadIdx.x >> 6;
    if ((threadIdx.x & 63) == 0) { red[wv] = s; red[4 + wv] = s2; }
    __syncthreads();
    s  = red[0] + red[1] + red[2] + red[3];
    s2 = red[4] + red[5] + red[6] + red[7];
    float mu  = s * (1.0f / 1024.0f);
    float var = s2 * (1.0f / 1024.0f) - mu * mu;
    float rs  = rsqrtf(var + 1e-5f);
    float4 g  = ((const float4*)gam)[threadIdx.x];
    float4 be = ((const float4*)bet)[threadIdx.x];
    ushort4 o;
    o.x = f2bf((x.x - mu) * rs * g.x + be.x);
    o.y = f2bf((x.y - mu) * rs * g.y + be.y);
    o.z = f2bf((x.z - mu) * rs * g.z + be.z);
    o.w = f2bf((x.w - mu) * rs * g.w + be.w);
    ((ushort4*)dst)[(size_t)row * 256 + threadIdx.x] = o;
}

// ======== 256x256 NT GEMM, BK=32, 64KB LDS -> 2 blocks/CU, desync loop ======
// C[m][n] = sum_k A[m][k]*B[n][k]
// 1-D grid, nt-major (wg = nt*MT_ + mt), bijective XCD chunk swizzle (m204)
// so each XCD's resident blocks share one B panel (fits 4MB L2).
// LDS: [2 buf][A0,A1,B0,B1][128 rows x 32 cols]; 64B rows.
// Swizzle: byte l -> l ^ (((l>>7)&3)<<4)   (2-way residual = free)
// MODE 0: QKV -> bf16 [B,H,S,D] (q scaled 1/8); MODE 1: f32 acc+bias+res;
// MODE 2: bf16 gelu(acc+bias)
template<int MODE>
__global__ __launch_bounds__(512, 4)
void gemmK(const u16* __restrict__ A,
           const u16* __restrict__ Bq, const u16* __restrict__ Bk, const u16* __restrict__ Bv,
           const float* __restrict__ biasq, const float* __restrict__ biask, const float* __restrict__ biasvv,
           const float* __restrict__ res, float* __restrict__ outF,
           u16* __restrict__ outBq, u16* __restrict__ outBk, u16* __restrict__ outBv,
           int M, int N, int K)
{
    __shared__ u16 lds[2][4][4096];   // [buf][A0,A1,B0,B1][128x32] = 64 KB
    const int tid = threadIdx.x, lane = tid & 63, w = tid >> 6;
    const int lr = lane & 15, lg = lane >> 4;
    const int wm = w >> 2, wn = w & 3;          // 2 x 4 wave grid

    // --- bijective XCD chunk swizzle over 1-D nt-major grid ---
    const int nwg = gridDim.x;
    const int q8 = nwg >> 3, r8 = nwg & 7;
    const int xcd = blockIdx.x & 7, o8 = blockIdx.x >> 3;
    const int wg = (xcd < r8 ? xcd * (q8 + 1) : r8 * (q8 + 1) + (xcd - r8) * q8) + o8;
    int nt = wg / MT_;
    const int mt = wg - nt * MT_;

    const u16* Bm = Bq; const float* bias = biasq; u16* outB = outBq;
    float scl = 1.0f;
    if (MODE == 0) {
        int mat = nt >> 2; nt &= 3;
        if (mat == 1)      { Bm = Bk; bias = biask; outB = outBk; }
        else if (mat == 2) { Bm = Bv; bias = biasvv; outB = outBv; }
        if (mat == 0) scl = 0.125f;             // D^-0.5
    }
    const int m0 = mt * 256, n0 = nt * 256;
    const int NTt = K >> 5;                     // 32-K tiles

    // staging: phys byte p (within 8KB seg... here 4KB seg x? seg=8KB? seg is
    // 128x32x2B = 8KB) -> logical l via involution; 512 thr x 16B = 8KB.
    const int p    = tid * 16;                  // 0..8191
    const int l_   = p ^ (((p >> 7) & 3) << 4);
    const int srow = l_ >> 6;                   // 0..127
    const int scol = (l_ & 63) >> 1;            // elem col, 8-aligned

    auto STAGE4 = [&](int buf, int t) {
        const int kc = t << 5;
        {   int gr = m0 + srow;       if (gr > M - 1) gr = M - 1;
            gload16(A  + (size_t)gr * K + kc + scol, (char*)&lds[buf][0][0] + p); }
        {   int gr = m0 + 128 + srow; if (gr > M - 1) gr = M - 1;
            gload16(A  + (size_t)gr * K + kc + scol, (char*)&lds[buf][1][0] + p); }
        {   int gr = n0 + srow;       if (gr > N - 1) gr = N - 1;
            gload16(Bm + (size_t)gr * K + kc + scol, (char*)&lds[buf][2][0] + p); }
        {   int gr = n0 + 128 + srow; if (gr > N - 1) gr = N - 1;
            gload16(Bm + (size_t)gr * K + kc + scol, (char*)&lds[buf][3][0] + p); }
    };
    auto LDA = [&](int buf, int mh, int mf) -> s16x8 {
        const char* b = (const char*)&lds[buf][wm][0];
        int inrow = mh * 64 + mf * 16 + lr;
        return *(const s16x8*)(b + inrow * 64 + ((lg * 16) ^ (((inrow >> 1) & 3) << 4)));
    };
    auto LDB = [&](int buf, int nf) -> s16x8 {
        const char* b = (const char*)&lds[buf][2 + (wn >> 1)][0];
        int inrow = (wn & 1) * 64 + nf * 16 + lr;
        return *(const s16x8*)(b + inrow * 64 + ((lg * 16) ^ (((inrow >> 1) & 3) << 4)));
    };

    f32x4 acc[8][4];
#pragma unroll
    for (int i = 0; i < 8; ++i)
#pragma unroll
        for (int j = 0; j < 4; ++j) { f32x4 z = {0.f, 0.f, 0.f, 0.f}; acc[i][j] = z; }

    // prologue: stage t0,t1 (8 loads); wait t0 (leave t1's 4 in flight)
    STAGE4(0, 0);
    STAGE4(1, 1);
    VMC4;
    BAR();

    for (int t = 0; t < NTt; ++t) {
        const int cur = t & 1;
        s16x8 bf[4];
#pragma unroll
        for (int nf = 0; nf < 4; ++nf) bf[nf] = LDB(cur, nf);
#pragma unroll
        for (int mh = 0; mh < 2; ++mh) {
            s16x8 af[4];
#pragma unroll
            for (int mf = 0; mf < 4; ++mf) af[mf] = LDA(cur, mh, mf);
#pragma unroll
            for (int mf = 0; mf < 4; ++mf)
#pragma unroll
                for (int nf = 0; nf < 4; ++nf)
                    acc[mh * 4 + mf][nf] = MFMA16(af[mf], bf[nf], acc[mh * 4 + mf][nf]);
        }
        BAR();                                   // all waves done with buf[cur]
        if (t + 2 < NTt) STAGE4(cur, t + 2);     // refill freed buffer
        if (t + 1 < NTt) {
            if (t + 2 < NTt) { VMC4; } else { VMC0; }   // tile t+1 landed
        }
        BAR();
    }

    // ---- epilogue ----
    float biasv[4];
#pragma unroll
    for (int nf = 0; nf < 4; ++nf)
        biasv[nf] = bias[n0 + wn * 64 + nf * 16 + lr];

#pragma unroll
    for (int am = 0; am < 8; ++am) {
#pragma unroll
        for (int r = 0; r < 4; ++r) {
            int row = m0 + wm * 128 + (am >> 2) * 64 + (am & 3) * 16 + lg * 4 + r;
            if (row >= M) continue;
            if (MODE == 0) {
                int bb = row / S_;
                int ss = row - bb * S_;
#pragma unroll
                for (int nf = 0; nf < 4; ++nf) {
                    int col = n0 + wn * 64 + nf * 16 + lr;
                    int hh = col >> 6, dd = col & 63;
                    float v = (acc[am][nf][r] + biasv[nf]) * scl;
                    outB[(((size_t)bb * H_ + hh) * S_ + ss) * D_ + dd] = f2bf(v);
                }
            } else if (MODE == 1) {
                size_t base = (size_t)row * N;
#pragma unroll
                for (int nf = 0; nf < 4; ++nf) {
                    int col = n0 + wn * 64 + nf * 16 + lr;
                    outF[base + col] = acc[am][nf][r] + biasv[nf] + res[base + col];
                }
            } else {
                size_t base = (size_t)row * N;
#pragma unroll
                for (int nf = 0; nf < 4; ++nf) {
                    int col = n0 + wn * 64 + nf * 16 + lr;
                    float x = acc[am][nf][r] + biasv[nf];
                    float u2 = 1.5957691216057308f * (x + 0.044715f * x * x * x);
                    u2 = fminf(u2, 80.0f);
                    float tt = __expf(u2);          // gelu = x * t / (1 + t)
                    outB[base + col] = f2bf(x * tt / (1.0f + tt));
                }
            }
        }
    }
}

// ---------------- fused attention: one WG per (b,h) ----------------
__global__ __launch_bounds__(256)
void attn_kernel(const u16* __restrict__ qg_, const u16* __restrict__ kg_,
                 const u16* __restrict__ vg_, const u16* __restrict__ msum,
                 u16* __restrict__ ctx)
{
    __shared__ u16 Ks[272 * 72];
    __shared__ u16 Vt[64 * 296];
    __shared__ u16 Ps[4][16 * 32];
    const int bh = blockIdx.x;
    const int b = bh >> 4, hh = bh & 15;
    const u16* kg = kg_ + (size_t)bh * (S_ * D_);
    const u16* vg = vg_ + (size_t)bh * (S_ * D_);
    const u16* qg = qg_ + (size_t)bh * (S_ * D_);
    const int tid = threadIdx.x, lane = tid & 63, wv = tid >> 6;

    for (int c = tid; c < (S_ * D_) / 8; c += 256) {
        int s = c >> 3, d8 = (c & 7) << 3;
        s16x8 val = *(const s16x8*)(kg + s * 64 + d8);
        *(s16x8*)&Ks[s * 72 + d8] = val;
    }
    for (int idx = tid; idx < 15 * 64; idx += 256) {
        int rr = 257 + (idx >> 6), cc = idx & 63;
        Ks[rr * 72 + cc] = 0;
    }
    for (int c = tid; c < (S_ * D_) / 8; c += 256) {
        int s = c >> 3, d8 = (c & 7) << 3;
        s16x8 val = *(const s16x8*)(vg + s * 64 + d8);
#pragma unroll
        for (int j = 0; j < 8; ++j) Vt[(d8 + j) * 296 + s] = (u16)val[j];
    }
    for (int idx = tid; idx < 64 * 39; idx += 256) {
        int dd = idx / 39, cc = 257 + idx % 39;
        Vt[dd * 296 + cc] = 0;
    }
    __syncthreads();

    const int lr = lane & 15, lg = lane >> 4;
    for (int qb = wv; qb < 17; qb += 4) {
        const int q0 = qb * 16;
        int qrow = q0 + lr; if (qrow > S_ - 1) qrow = S_ - 1;
        s16x8 aq0 = *(const s16x8*)(qg + qrow * 64 + lg * 8);
        s16x8 aq1 = *(const s16x8*)(qg + qrow * 64 + 32 + lg * 8);

        f32x4 sc[17];
#pragma unroll
        for (int t = 0; t < 17; ++t) { f32x4 z = {0.f, 0.f, 0.f, 0.f}; sc[t] = z; }
#pragma unroll
        for (int t = 0; t < 17; ++t) {
            s16x8 b0 = *(const s16x8*)&Ks[(t * 16 + lr) * 72 + lg * 8];
            s16x8 b1 = *(const s16x8*)&Ks[(t * 16 + lr) * 72 + 32 + lg * 8];
            sc[t] = MFMA16(aq0, b0, sc[t]);
            sc[t] = MFMA16(aq1, b1, sc[t]);
        }
        float mx[4] = {-3e38f, -3e38f, -3e38f, -3e38f};
#pragma unroll
        for (int r = 0; r < 4; ++r) {
            int sq = q0 + lg * 4 + r; if (sq > S_ - 1) sq = S_ - 1;
            const u16* mrow = msum + ((size_t)b * S_ + sq) * 272;
#pragma unroll
            for (int t = 0; t < 17; ++t) {
                sc[t][r] += bf2f(mrow[t * 16 + lr]);
                mx[r] = fmaxf(mx[r], sc[t][r]);
            }
        }
#pragma unroll
        for (int r = 0; r < 4; ++r) {
#pragma unroll
            for (int xm = 1; xm <= 8; xm <<= 1)
                mx[r] = fmaxf(mx[r], __shfl_xor(mx[r], xm, 64));
        }
        float sum[4] = {0.f, 0.f, 0.f, 0.f};
#pragma unroll
        for (int t = 0; t < 17; ++t)
#pragma unroll
            for (int r = 0; r < 4; ++r) {
                float e = __expf(sc[t][r] - mx[r]);
                sc[t][r] = e; sum[r] += e;
            }
#pragma unroll
        for (int r = 0; r < 4; ++r) {
#pragma unroll
            for (int xm = 1; xm <= 8; xm <<= 1)
                sum[r] += __shfl_xor(sum[r], xm, 64);
        }

        f32x4 ac[4];
#pragma unroll
        for (int nt = 0; nt < 4; ++nt) { f32x4 z = {0.f, 0.f, 0.f, 0.f}; ac[nt] = z; }
        u16* myP = &Ps[wv][0];
#pragma unroll
        for (int kc = 0; kc < 9; ++kc) {
#pragma unroll
            for (int tt = 0; tt < 2; ++tt) {
                const int t = kc * 2 + tt;
#pragma unroll
                for (int r = 0; r < 4; ++r) {
                    float pv = (t < 17) ? sc[(t < 17) ? t : 0][r] : 0.f;
                    myP[(lg * 4 + r) * 32 + tt * 16 + lr] = f2bf(pv);
                }
            }
            s16x8 pa = *(const s16x8*)&myP[lr * 32 + lg * 8];
#pragma unroll
            for (int nt = 0; nt < 4; ++nt) {
                s16x8 bv = *(const s16x8*)&Vt[(nt * 16 + lr) * 296 + kc * 32 + lg * 8];
                ac[nt] = MFMA16(pa, bv, ac[nt]);
            }
        }
#pragma unroll
        for (int r = 0; r < 4; ++r) {
            int sq = q0 + lg * 4 + r;
            if (sq < S_) {
                float rd = 1.0f / sum[r];
                size_t base = (((size_t)b * S_ + sq) * H_ + hh) * D_;
#pragma unroll
                for (int nt = 0; nt < 4; ++nt)
                    ctx[base + nt * 16 + lr] = f2bf(ac[nt][r] * rd);
            }
        }
    }
}

// ---------------- launch ----------------
extern "C" void kernel_launch(void* const* d_in, const int* in_sizes, int n_in,
                              void* d_out, int out_size, void* d_ws, size_t ws_size,
                              hipStream_t stream)
{
    const float* hid   = (const float*)d_in[0];
    const float* am    = (const float*)d_in[1];
    const float* cm    = (const float*)d_in[2];
    const float* ln1w  = (const float*)d_in[3];
    const float* ln1b  = (const float*)d_in[4];
    const float* qw    = (const float*)d_in[5];
    const float* qbias = (const float*)d_in[6];
    const float* kw    = (const float*)d_in[7];
    const float* kbias = (const float*)d_in[8];
    const float* vw    = (const float*)d_in[9];
    const float* vbias = (const float*)d_in[10];
    const float* ow    = (const float*)d_in[11];
    const float* obias = (const float*)d_in[12];
    const float* ln2w  = (const float*)d_in[13];
    const float* ln2b  = (const float*)d_in[14];
    const float* f1w   = (const float*)d_in[15];
    const float* f1b   = (const float*)d_in[16];
    const float* f2w   = (const float*)d_in[17];
    const float* f2b   = (const float*)d_in[18];
    float* out = (float*)d_out;

    const size_t ME = (size_t)M_ * E_;
    u16* Wq   = (u16*)d_ws;
    u16* Wk   = Wq + 1048576;
    u16* Wv   = Wk + 1048576;
    u16* Wo   = Wv + 1048576;
    u16* Wf1  = Wo + 1048576;
    u16* Wf2  = Wf1 + 4 * 1048576;
    u16* xln  = Wf2 + 4 * 1048576;
    u16* qb_  = xln + ME;
    u16* kb_  = qb_ + ME;
    u16* vb_  = kb_ + ME;
    u16* ctx  = vb_ + ME;
    float* hbuf = (float*)(ctx + ME);
    u16* msum = (u16*)(hbuf + ME);
    u16* act  = qb_;      // reuse q..ctx region = M x I bf16 (exact fit)
    u16* x2   = xln;

    convert_w_kernel<<<3072, 256, 0, stream>>>(qw, kw, vw, ow, f1w, f2w, Wq);
    mask_combine_kernel<<<8736, 256, 0, stream>>>(am, cm, msum);
    ln_kernel<<<M_, 256, 0, stream>>>(hid, ln1w, ln1b, xln);
    gemmK<0><<<12 * MT_, 512, 0, stream>>>(xln, Wq, Wk, Wv, qbias, kbias, vbias,
                                           nullptr, nullptr, qb_, kb_, vb_,
                                           M_, 1024, 1024);
    attn_kernel<<<512, 256, 0, stream>>>(qb_, kb_, vb_, msum, ctx);
    gemmK<1><<<4 * MT_, 512, 0, stream>>>(ctx, Wo, nullptr, nullptr, obias, nullptr, nullptr,
                                          hid, hbuf, nullptr, nullptr, nullptr,
                                          M_, 1024, 1024);
    ln_kernel<<<M_, 256, 0, stream>>>(hbuf, ln2w, ln2b, x2);
    gemmK<2><<<16 * MT_, 512, 0, stream>>>(x2, Wf1, nullptr, nullptr, f1b, nullptr, nullptr,
                                           nullptr, nullptr, act, nullptr, nullptr,
                                           M_, 4096, 1024);
    gemmK<1><<<4 * MT_, 512, 0, stream>>>(act, Wf2, nullptr, nullptr, f2b, nullptr, nullptr,
                                          hbuf, out, nullptr, nullptr, nullptr,
                                          M_, 1024, 4096);
}

// Round 8
// 456.630 us; speedup vs baseline: 3.6111x; 3.6111x over previous
//
#include <hip/hip_runtime.h>

typedef unsigned short u16;
typedef unsigned int   u32;
typedef short s16x8 __attribute__((ext_vector_type(8)));
typedef float f32x4 __attribute__((ext_vector_type(4)));

#define MFMA16(A,B,C) __builtin_amdgcn_mfma_f32_16x16x32_bf16((A),(B),(C),0,0,0)
#define BAR()  asm volatile("s_barrier" ::: "memory")
#define VMC4   asm volatile("s_waitcnt vmcnt(4)" ::: "memory")
#define VMC0   asm volatile("s_waitcnt vmcnt(0)" ::: "memory")

#define B_   32
#define S_   257
#define E_   1024
#define H_   16
#define D_   64
#define I_   4096
#define M_   (B_*S_)   // 8224

__device__ __forceinline__ u16 f2bf(float f) {
    u32 u = __float_as_uint(f);
    u32 r = u + 0x7fffu + ((u >> 16) & 1u);
    return (u16)(r >> 16);
}
__device__ __forceinline__ float bf2f(u16 b) {
    return __uint_as_float(((u32)b) << 16);
}

__device__ __forceinline__ void gload16(const void* g, void* l) {
    __builtin_amdgcn_global_load_lds(
        (const __attribute__((address_space(1))) u32*)g,
        (__attribute__((address_space(3))) u32*)l, 16, 0, 0);
}

// ---------------- weight fp32 -> bf16 convert (12M elems) ----------------
__global__ __launch_bounds__(256)
void convert_w_kernel(const float* __restrict__ qw, const float* __restrict__ kw,
                      const float* __restrict__ vw, const float* __restrict__ ow,
                      const float* __restrict__ f1, const float* __restrict__ f2,
                      u16* __restrict__ dst)
{
    const int total4 = (12 * 1048576) / 4;
    for (int i = blockIdx.x * 256 + threadIdx.x; i < total4; i += gridDim.x * 256) {
        int e = i * 4;
        int seg = e >> 20;
        const float* srcp; int off;
        if (seg < 4)      { srcp = (seg == 0 ? qw : seg == 1 ? kw : seg == 2 ? vw : ow); off = e & 1048575; }
        else if (seg < 8) { srcp = f1; off = e - 4 * 1048576; }
        else              { srcp = f2; off = e - 8 * 1048576; }
        float4 v = *(const float4*)(srcp + off);
        ushort4 o;
        o.x = f2bf(v.x); o.y = f2bf(v.y); o.z = f2bf(v.z); o.w = f2bf(v.w);
        *(ushort4*)(dst + e) = o;
    }
}

// ---------------- combined mask table: msum[b][sq][272] bf16 ----------------
__global__ __launch_bounds__(256)
void mask_combine_kernel(const float* __restrict__ am, const float* __restrict__ cm,
                         u16* __restrict__ msum)
{
    const int total = B_ * S_ * 272;
    for (int i = blockIdx.x * 256 + threadIdx.x; i < total; i += gridDim.x * 256) {
        int skv = i % 272;
        int rem = i / 272;
        int sq  = rem % S_;
        int b   = rem / S_;
        float v;
        if (skv < S_) {
            size_t o = ((size_t)b * S_ + sq) * S_ + skv;
            v = am[o] + cm[o];
        } else v = -1e30f;
        msum[i] = f2bf(v);
    }
}

// ---------------- LayerNorm row kernel ----------------
__global__ __launch_bounds__(256)
void ln_kernel(const float* __restrict__ src, const float* __restrict__ gam,
               const float* __restrict__ bet, u16* __restrict__ dst)
{
    int row = blockIdx.x;
    const float4* p = (const float4*)(src + (size_t)row * E_);
    float4 x = p[threadIdx.x];
    float s  = x.x + x.y + x.z + x.w;
    float s2 = x.x * x.x + x.y * x.y + x.z * x.z + x.w * x.w;
#pragma unroll
    for (int xm = 1; xm < 64; xm <<= 1) {
        s  += __shfl_xor(s,  xm, 64);
        s2 += __shfl_xor(s2, xm, 64);
    }
    __shared__ float red[8];
    int wv = threadIdx.x >> 6;
    if ((threadIdx.x & 63) == 0) { red[wv] = s; red[4 + wv] = s2; }
    __syncthreads();
    s  = red[0] + red[1] + red[2] + red[3];
    s2 = red[4] + red[5] + red[6] + red[7];
    float mu  = s * (1.0f / 1024.0f);
    float var = s2 * (1.0f / 1024.0f) - mu * mu;
    float rs  = rsqrtf(var + 1e-5f);
    float4 g  = ((const float4*)gam)[threadIdx.x];
    float4 be = ((const float4*)bet)[threadIdx.x];
    ushort4 o;
    o.x = f2bf((x.x - mu) * rs * g.x + be.x);
    o.y = f2bf((x.y - mu) * rs * g.y + be.y);
    o.z = f2bf((x.z - mu) * rs * g.z + be.z);
    o.w = f2bf((x.w - mu) * rs * g.w + be.w);
    ((ushort4*)dst)[(size_t)row * 256 + threadIdx.x] = o;
}

// ======== 128x128 NT GEMM, BK=32, 4 waves, 32KB LDS -> 3 blocks/CU ==========
// m97 shape (16 MFMA + 8 ds_read_b128 per k-step) + XOR swizzle (conflicts=0)
// + post-compute staging of tile t+2 with counted vmcnt(4).
// Grid: x = mt (65), y = nt [MODE0: y = mat*8 + nt].
// MODE 0: QKV -> bf16 [B,H,S,D] (q scaled 1/8); MODE 1: f32 acc+bias+res;
// MODE 2: bf16 gelu(acc+bias)
template<int MODE>
__global__ __launch_bounds__(256, 3)
void gemm4(const u16* __restrict__ A,
           const u16* __restrict__ Bq, const u16* __restrict__ Bk, const u16* __restrict__ Bv,
           const float* __restrict__ biasq, const float* __restrict__ biask, const float* __restrict__ biasvv,
           const float* __restrict__ res, float* __restrict__ outF,
           u16* __restrict__ outBq, u16* __restrict__ outBk, u16* __restrict__ outBv,
           int M, int N, int K)
{
    __shared__ u16 lds[2][2][4096];   // [buf][A,B][128 rows x 32 cols] = 32 KB
    const int tid = threadIdx.x, lane = tid & 63, w = tid >> 6;
    const int lr = lane & 15, lg = lane >> 4;
    const int wm = w >> 1, wn = w & 1;          // 2 x 2 wave grid

    const u16* Bm = Bq; const float* bias = biasq; u16* outB = outBq;
    float scl = 1.0f;
    int nt = blockIdx.y;
    if (MODE == 0) {
        int mat = nt >> 3; nt &= 7;
        if (mat == 1)      { Bm = Bk; bias = biask; outB = outBk; }
        else if (mat == 2) { Bm = Bv; bias = biasvv; outB = outBv; }
        if (mat == 0) scl = 0.125f;             // D^-0.5
    }
    const int m0 = blockIdx.x * 128, n0 = nt * 128;
    const int NTt = K >> 5;                     // 32-K tiles

    // staging: phys byte p in 4KB segment -> logical l via involution
    const int p    = tid * 16;                  // 0..4095
    const int l_   = p ^ (((p >> 7) & 3) << 4);
    const int srow = l_ >> 6;                   // 0..63
    const int scol = (l_ & 63) >> 1;            // elem col, 8-aligned
    const int wbase = w * 1024;                 // wave-uniform LDS offset

    auto STAGE = [&](int buf, int t) {
        const int kc = t << 5;
        {   int gr = m0 + srow;       if (gr > M - 1) gr = M - 1;
            gload16(A  + (size_t)gr * K + kc + scol, (char*)&lds[buf][0][0] + wbase); }
        {   int gr = m0 + 64 + srow;  if (gr > M - 1) gr = M - 1;
            gload16(A  + (size_t)gr * K + kc + scol, (char*)&lds[buf][0][0] + 4096 + wbase); }
        {   int gr = n0 + srow;       if (gr > N - 1) gr = N - 1;
            gload16(Bm + (size_t)gr * K + kc + scol, (char*)&lds[buf][1][0] + wbase); }
        {   int gr = n0 + 64 + srow;  if (gr > N - 1) gr = N - 1;
            gload16(Bm + (size_t)gr * K + kc + scol, (char*)&lds[buf][1][0] + 4096 + wbase); }
    };
    auto LDA = [&](int buf, int mf) -> s16x8 {
        const char* b = (const char*)&lds[buf][0][0];
        int row = wm * 64 + mf * 16 + lr;
        return *(const s16x8*)(b + row * 64 + ((lg * 16) ^ (((row >> 1) & 3) << 4)));
    };
    auto LDB = [&](int buf, int nf) -> s16x8 {
        const char* b = (const char*)&lds[buf][1][0];
        int row = wn * 64 + nf * 16 + lr;
        return *(const s16x8*)(b + row * 64 + ((lg * 16) ^ (((row >> 1) & 3) << 4)));
    };

    f32x4 acc[4][4];
#pragma unroll
    for (int i = 0; i < 4; ++i)
#pragma unroll
        for (int j = 0; j < 4; ++j) { f32x4 z = {0.f, 0.f, 0.f, 0.f}; acc[i][j] = z; }

    // prologue: stage t0,t1 (8 loads/thread-wave); wait t0 (t1's 4 in flight)
    STAGE(0, 0);
    STAGE(1, 1);
    VMC4;
    BAR();

    for (int t = 0; t < NTt; ++t) {
        const int cur = t & 1;
        s16x8 bf[4], af[4];
#pragma unroll
        for (int nf = 0; nf < 4; ++nf) bf[nf] = LDB(cur, nf);
#pragma unroll
        for (int mf = 0; mf < 4; ++mf) af[mf] = LDA(cur, mf);
#pragma unroll
        for (int mf = 0; mf < 4; ++mf)
#pragma unroll
            for (int nf = 0; nf < 4; ++nf)
                acc[mf][nf] = MFMA16(af[mf], bf[nf], acc[mf][nf]);
        BAR();                                   // all waves done with buf[cur]
        if (t + 2 < NTt) STAGE(cur, t + 2);      // refill freed buffer
        if (t + 1 < NTt) {
            if (t + 2 < NTt) { VMC4; } else { VMC0; }   // tile t+1 landed
        }
        BAR();
    }

    // ---- epilogue ----
    float biasv[4];
#pragma unroll
    for (int nf = 0; nf < 4; ++nf)
        biasv[nf] = bias[n0 + wn * 64 + nf * 16 + lr];

#pragma unroll
    for (int mf = 0; mf < 4; ++mf) {
#pragma unroll
        for (int r = 0; r < 4; ++r) {
            int row = m0 + wm * 64 + mf * 16 + lg * 4 + r;
            if (row >= M) continue;
            if (MODE == 0) {
                int bb = row / S_;
                int ss = row - bb * S_;
#pragma unroll
                for (int nf = 0; nf < 4; ++nf) {
                    int col = n0 + wn * 64 + nf * 16 + lr;
                    int hh = col >> 6, dd = col & 63;
                    float v = (acc[mf][nf][r] + biasv[nf]) * scl;
                    outB[(((size_t)bb * H_ + hh) * S_ + ss) * D_ + dd] = f2bf(v);
                }
            } else if (MODE == 1) {
                size_t base = (size_t)row * N;
#pragma unroll
                for (int nf = 0; nf < 4; ++nf) {
                    int col = n0 + wn * 64 + nf * 16 + lr;
                    outF[base + col] = acc[mf][nf][r] + biasv[nf] + res[base + col];
                }
            } else {
                size_t base = (size_t)row * N;
#pragma unroll
                for (int nf = 0; nf < 4; ++nf) {
                    int col = n0 + wn * 64 + nf * 16 + lr;
                    float x = acc[mf][nf][r] + biasv[nf];
                    float u2 = 1.5957691216057308f * (x + 0.044715f * x * x * x);
                    u2 = fminf(u2, 80.0f);
                    float tt = __expf(u2);          // gelu = x * t / (1 + t)
                    outB[base + col] = f2bf(x * tt / (1.0f + tt));
                }
            }
        }
    }
}

// ---------------- fused attention: one WG per (b,h) ----------------
__global__ __launch_bounds__(256)
void attn_kernel(const u16* __restrict__ qg_, const u16* __restrict__ kg_,
                 const u16* __restrict__ vg_, const u16* __restrict__ msum,
                 u16* __restrict__ ctx)
{
    __shared__ u16 Ks[272 * 72];
    __shared__ u16 Vt[64 * 296];
    __shared__ u16 Ps[4][16 * 32];
    const int bh = blockIdx.x;
    const int b = bh >> 4, hh = bh & 15;
    const u16* kg = kg_ + (size_t)bh * (S_ * D_);
    const u16* vg = vg_ + (size_t)bh * (S_ * D_);
    const u16* qg = qg_ + (size_t)bh * (S_ * D_);
    const int tid = threadIdx.x, lane = tid & 63, wv = tid >> 6;

    for (int c = tid; c < (S_ * D_) / 8; c += 256) {
        int s = c >> 3, d8 = (c & 7) << 3;
        s16x8 val = *(const s16x8*)(kg + s * 64 + d8);
        *(s16x8*)&Ks[s * 72 + d8] = val;
    }
    for (int idx = tid; idx < 15 * 64; idx += 256) {
        int rr = 257 + (idx >> 6), cc = idx & 63;
        Ks[rr * 72 + cc] = 0;
    }
    for (int c = tid; c < (S_ * D_) / 8; c += 256) {
        int s = c >> 3, d8 = (c & 7) << 3;
        s16x8 val = *(const s16x8*)(vg + s * 64 + d8);
#pragma unroll
        for (int j = 0; j < 8; ++j) Vt[(d8 + j) * 296 + s] = (u16)val[j];
    }
    for (int idx = tid; idx < 64 * 39; idx += 256) {
        int dd = idx / 39, cc = 257 + idx % 39;
        Vt[dd * 296 + cc] = 0;
    }
    __syncthreads();

    const int lr = lane & 15, lg = lane >> 4;
    for (int qb = wv; qb < 17; qb += 4) {
        const int q0 = qb * 16;
        int qrow = q0 + lr; if (qrow > S_ - 1) qrow = S_ - 1;
        s16x8 aq0 = *(const s16x8*)(qg + qrow * 64 + lg * 8);
        s16x8 aq1 = *(const s16x8*)(qg + qrow * 64 + 32 + lg * 8);

        f32x4 sc[17];
#pragma unroll
        for (int t = 0; t < 17; ++t) { f32x4 z = {0.f, 0.f, 0.f, 0.f}; sc[t] = z; }
#pragma unroll
        for (int t = 0; t < 17; ++t) {
            s16x8 b0 = *(const s16x8*)&Ks[(t * 16 + lr) * 72 + lg * 8];
            s16x8 b1 = *(const s16x8*)&Ks[(t * 16 + lr) * 72 + 32 + lg * 8];
            sc[t] = MFMA16(aq0, b0, sc[t]);
            sc[t] = MFMA16(aq1, b1, sc[t]);
        }
        float mx[4] = {-3e38f, -3e38f, -3e38f, -3e38f};
#pragma unroll
        for (int r = 0; r < 4; ++r) {
            int sq = q0 + lg * 4 + r; if (sq > S_ - 1) sq = S_ - 1;
            const u16* mrow = msum + ((size_t)b * S_ + sq) * 272;
#pragma unroll
            for (int t = 0; t < 17; ++t) {
                sc[t][r] += bf2f(mrow[t * 16 + lr]);
                mx[r] = fmaxf(mx[r], sc[t][r]);
            }
        }
#pragma unroll
        for (int r = 0; r < 4; ++r) {
#pragma unroll
            for (int xm = 1; xm <= 8; xm <<= 1)
                mx[r] = fmaxf(mx[r], __shfl_xor(mx[r], xm, 64));
        }
        float sum[4] = {0.f, 0.f, 0.f, 0.f};
#pragma unroll
        for (int t = 0; t < 17; ++t)
#pragma unroll
            for (int r = 0; r < 4; ++r) {
                float e = __expf(sc[t][r] - mx[r]);
                sc[t][r] = e; sum[r] += e;
            }
#pragma unroll
        for (int r = 0; r < 4; ++r) {
#pragma unroll
            for (int xm = 1; xm <= 8; xm <<= 1)
                sum[r] += __shfl_xor(sum[r], xm, 64);
        }

        f32x4 ac[4];
#pragma unroll
        for (int nt = 0; nt < 4; ++nt) { f32x4 z = {0.f, 0.f, 0.f, 0.f}; ac[nt] = z; }
        u16* myP = &Ps[wv][0];
#pragma unroll
        for (int kc = 0; kc < 9; ++kc) {
#pragma unroll
            for (int tt = 0; tt < 2; ++tt) {
                const int t = kc * 2 + tt;
#pragma unroll
                for (int r = 0; r < 4; ++r) {
                    float pv = (t < 17) ? sc[(t < 17) ? t : 0][r] : 0.f;
                    myP[(lg * 4 + r) * 32 + tt * 16 + lr] = f2bf(pv);
                }
            }
            s16x8 pa = *(const s16x8*)&myP[lr * 32 + lg * 8];
#pragma unroll
            for (int nt = 0; nt < 4; ++nt) {
                s16x8 bv = *(const s16x8*)&Vt[(nt * 16 + lr) * 296 + kc * 32 + lg * 8];
                ac[nt] = MFMA16(pa, bv, ac[nt]);
            }
        }
#pragma unroll
        for (int r = 0; r < 4; ++r) {
            int sq = q0 + lg * 4 + r;
            if (sq < S_) {
                float rd = 1.0f / sum[r];
                size_t base = (((size_t)b * S_ + sq) * H_ + hh) * D_;
#pragma unroll
                for (int nt = 0; nt < 4; ++nt)
                    ctx[base + nt * 16 + lr] = f2bf(ac[nt][r] * rd);
            }
        }
    }
}

// ---------------- launch ----------------
extern "C" void kernel_launch(void* const* d_in, const int* in_sizes, int n_in,
                              void* d_out, int out_size, void* d_ws, size_t ws_size,
                              hipStream_t stream)
{
    const float* hid   = (const float*)d_in[0];
    const float* am    = (const float*)d_in[1];
    const float* cm    = (const float*)d_in[2];
    const float* ln1w  = (const float*)d_in[3];
    const float* ln1b  = (const float*)d_in[4];
    const float* qw    = (const float*)d_in[5];
    const float* qbias = (const float*)d_in[6];
    const float* kw    = (const float*)d_in[7];
    const float* kbias = (const float*)d_in[8];
    const float* vw    = (const float*)d_in[9];
    const float* vbias = (const float*)d_in[10];
    const float* ow    = (const float*)d_in[11];
    const float* obias = (const float*)d_in[12];
    const float* ln2w  = (const float*)d_in[13];
    const float* ln2b  = (const float*)d_in[14];
    const float* f1w   = (const float*)d_in[15];
    const float* f1b   = (const float*)d_in[16];
    const float* f2w   = (const float*)d_in[17];
    const float* f2b   = (const float*)d_in[18];
    float* out = (float*)d_out;

    const size_t ME = (size_t)M_ * E_;
    u16* Wq   = (u16*)d_ws;
    u16* Wk   = Wq + 1048576;
    u16* Wv   = Wk + 1048576;
    u16* Wo   = Wv + 1048576;
    u16* Wf1  = Wo + 1048576;
    u16* Wf2  = Wf1 + 4 * 1048576;
    u16* xln  = Wf2 + 4 * 1048576;
    u16* qb_  = xln + ME;
    u16* kb_  = qb_ + ME;
    u16* vb_  = kb_ + ME;
    u16* ctx  = vb_ + ME;
    float* hbuf = (float*)(ctx + ME);
    u16* msum = (u16*)(hbuf + ME);
    u16* act  = qb_;      // reuse q..ctx region = M x I bf16 (exact fit)
    u16* x2   = xln;

    convert_w_kernel<<<3072, 256, 0, stream>>>(qw, kw, vw, ow, f1w, f2w, Wq);
    mask_combine_kernel<<<8736, 256, 0, stream>>>(am, cm, msum);
    ln_kernel<<<M_, 256, 0, stream>>>(hid, ln1w, ln1b, xln);
    gemm4<0><<<dim3(65, 24), 256, 0, stream>>>(xln, Wq, Wk, Wv, qbias, kbias, vbias,
                                               nullptr, nullptr, qb_, kb_, vb_,
                                               M_, 1024, 1024);
    attn_kernel<<<512, 256, 0, stream>>>(qb_, kb_, vb_, msum, ctx);
    gemm4<1><<<dim3(65, 8), 256, 0, stream>>>(ctx, Wo, nullptr, nullptr, obias, nullptr, nullptr,
                                              hid, hbuf, nullptr, nullptr, nullptr,
                                              M_, 1024, 1024);
    ln_kernel<<<M_, 256, 0, stream>>>(hbuf, ln2w, ln2b, x2);
    gemm4<2><<<dim3(65, 32), 256, 0, stream>>>(x2, Wf1, nullptr, nullptr, f1b, nullptr, nullptr,
                                               nullptr, nullptr, act, nullptr, nullptr,
                                               M_, 4096, 1024);
    gemm4<1><<<dim3(65, 8), 256, 0, stream>>>(act, Wf2, nullptr, nullptr, f2b, nullptr, nullptr,
                                              hbuf, out, nullptr, nullptr, nullptr,
                                              M_, 1024, 4096);
}

// Round 9
// 427.571 us; speedup vs baseline: 3.8565x; 1.0680x over previous
//
#include <hip/hip_runtime.h>

typedef unsigned short u16;
typedef unsigned int   u32;
typedef short s16x8 __attribute__((ext_vector_type(8)));
typedef float f32x4 __attribute__((ext_vector_type(4)));

#define MFMA16(A,B,C) __builtin_amdgcn_mfma_f32_16x16x32_bf16((A),(B),(C),0,0,0)
#define BAR()  asm volatile("s_barrier" ::: "memory")
#define VMC6   asm volatile("s_waitcnt vmcnt(6)" ::: "memory")
#define VMC0   asm volatile("s_waitcnt vmcnt(0)" ::: "memory")

#define B_   32
#define S_   257
#define E_   1024
#define H_   16
#define D_   64
#define I_   4096
#define M_   (B_*S_)   // 8224
#define MT_  33        // ceil(M/256)

__device__ __forceinline__ u16 f2bf(float f) {
    u32 u = __float_as_uint(f);
    u32 r = u + 0x7fffu + ((u >> 16) & 1u);
    return (u16)(r >> 16);
}
__device__ __forceinline__ float bf2f(u16 b) {
    return __uint_as_float(((u32)b) << 16);
}

__device__ __forceinline__ void gload16(const void* g, void* l) {
    __builtin_amdgcn_global_load_lds(
        (const __attribute__((address_space(1))) u32*)g,
        (__attribute__((address_space(3))) u32*)l, 16, 0, 0);
}

// ---------------- weight fp32 -> bf16 convert (12M elems) ----------------
__global__ __launch_bounds__(256)
void convert_w_kernel(const float* __restrict__ qw, const float* __restrict__ kw,
                      const float* __restrict__ vw, const float* __restrict__ ow,
                      const float* __restrict__ f1, const float* __restrict__ f2,
                      u16* __restrict__ dst)
{
    const int total4 = (12 * 1048576) / 4;
    for (int i = blockIdx.x * 256 + threadIdx.x; i < total4; i += gridDim.x * 256) {
        int e = i * 4;
        int seg = e >> 20;
        const float* srcp; int off;
        if (seg < 4)      { srcp = (seg == 0 ? qw : seg == 1 ? kw : seg == 2 ? vw : ow); off = e & 1048575; }
        else if (seg < 8) { srcp = f1; off = e - 4 * 1048576; }
        else              { srcp = f2; off = e - 8 * 1048576; }
        float4 v = *(const float4*)(srcp + off);
        ushort4 o;
        o.x = f2bf(v.x); o.y = f2bf(v.y); o.z = f2bf(v.z); o.w = f2bf(v.w);
        *(ushort4*)(dst + e) = o;
    }
}

// ---------------- combined mask table: msum[b][sq][272] bf16 ----------------
__global__ __launch_bounds__(256)
void mask_combine_kernel(const float* __restrict__ am, const float* __restrict__ cm,
                         u16* __restrict__ msum)
{
    const int total = B_ * S_ * 272;
    for (int i = blockIdx.x * 256 + threadIdx.x; i < total; i += gridDim.x * 256) {
        int skv = i % 272;
        int rem = i / 272;
        int sq  = rem % S_;
        int b   = rem / S_;
        float v;
        if (skv < S_) {
            size_t o = ((size_t)b * S_ + sq) * S_ + skv;
            v = am[o] + cm[o];
        } else v = -1e30f;
        msum[i] = f2bf(v);
    }
}

// ---------------- LayerNorm row kernel ----------------
__global__ __launch_bounds__(256)
void ln_kernel(const float* __restrict__ src, const float* __restrict__ gam,
               const float* __restrict__ bet, u16* __restrict__ dst)
{
    int row = blockIdx.x;
    const float4* p = (const float4*)(src + (size_t)row * E_);
    float4 x = p[threadIdx.x];
    float s  = x.x + x.y + x.z + x.w;
    float s2 = x.x * x.x + x.y * x.y + x.z * x.z + x.w * x.w;
#pragma unroll
    for (int xm = 1; xm < 64; xm <<= 1) {
        s  += __shfl_xor(s,  xm, 64);
        s2 += __shfl_xor(s2, xm, 64);
    }
    __shared__ float red[8];
    int wv = threadIdx.x >> 6;
    if ((threadIdx.x & 63) == 0) { red[wv] = s; red[4 + wv] = s2; }
    __syncthreads();
    s  = red[0] + red[1] + red[2] + red[3];
    s2 = red[4] + red[5] + red[6] + red[7];
    float mu  = s * (1.0f / 1024.0f);
    float var = s2 * (1.0f / 1024.0f) - mu * mu;
    float rs  = rsqrtf(var + 1e-5f);
    float4 g  = ((const float4*)gam)[threadIdx.x];
    float4 be = ((const float4*)bet)[threadIdx.x];
    ushort4 o;
    o.x = f2bf((x.x - mu) * rs * g.x + be.x);
    o.y = f2bf((x.y - mu) * rs * g.y + be.y);
    o.z = f2bf((x.z - mu) * rs * g.z + be.z);
    o.w = f2bf((x.w - mu) * rs * g.w + be.w);
    ((ushort4*)dst)[(size_t)row * 256 + threadIdx.x] = o;
}

// ======== 256x128 NT GEMM, 4 waves x (128x64), BK=32, 48KB LDS ==============
// 2 blocks/CU (launch_bounds(256,2): VGPR cap 256, acc=128).  Desync loop,
// involution swizzle (conflicts ~0), 2-tile prefetch, counted vmcnt(6).
// LDS: [2 buf][6 seg][64 rows x 32 cols]; segs 0-3 = A rows 0..255,
// segs 4-5 = B rows 0..127.  Flat grid, mt-major, bijective XCD chunking.
// MODE 0: QKV -> bf16 [B,H,S,D] (q scaled 1/8); MODE 1: f32 acc+bias+res;
// MODE 2: bf16 gelu(acc+bias)
template<int MODE>
__global__ __launch_bounds__(256, 2)
void gemmW(const u16* __restrict__ A,
           const u16* __restrict__ Bq, const u16* __restrict__ Bk, const u16* __restrict__ Bv,
           const float* __restrict__ biasq, const float* __restrict__ biask, const float* __restrict__ biasvv,
           const float* __restrict__ res, float* __restrict__ outF,
           u16* __restrict__ outBq, u16* __restrict__ outBk, u16* __restrict__ outBv,
           int M, int N, int K)
{
    __shared__ u16 lds[2][6][2048];   // 48 KB
    const int tid = threadIdx.x, lane = tid & 63, w = tid >> 6;
    const int lr = lane & 15, lg = lane >> 4;
    const int wm = w >> 1, wn = w & 1;          // 2 x 2 wave grid

    // --- bijective XCD chunk swizzle over flat grid ---
    const int nwg = gridDim.x;
    const int q8 = nwg >> 3, r8 = nwg & 7;
    const int xcd = blockIdx.x & 7, o8 = blockIdx.x >> 3;
    int wg = (xcd < r8 ? xcd * (q8 + 1) : r8 * (q8 + 1) + (xcd - r8) * q8) + o8;

    const u16* Bm = Bq; const float* bias = biasq; u16* outB = outBq;
    float scl = 1.0f;
    const int NTL = N >> 7;                     // n-tiles per matrix
    if (MODE == 0) {
        int mat = wg / (MT_ * NTL); wg -= mat * (MT_ * NTL);
        if (mat == 1)      { Bm = Bk; bias = biask; outB = outBk; }
        else if (mat == 2) { Bm = Bv; bias = biasvv; outB = outBv; }
        if (mat == 0) scl = 0.125f;             // D^-0.5
    }
    const int mt = wg / NTL, nt = wg - mt * NTL;   // mt-major (nt fastest)
    const int m0 = mt * 256, n0 = nt * 128;
    const int NTt = K >> 5;                     // 32-K tiles

    // staging: phys byte p in 4KB segment -> logical l via involution
    const int p    = tid * 16;                  // 0..4095
    const int l_   = p ^ (((p >> 7) & 3) << 4);
    const int srow = l_ >> 6;                   // 0..63
    const int scol = (l_ & 63) >> 1;            // elem col, 8-aligned
    const int wbase = w * 1024;                 // wave-uniform LDS offset

    auto STAGE = [&](int buf, int t) {
        const int kc = t << 5;
#pragma unroll
        for (int s = 0; s < 4; ++s) {
            int gr = m0 + s * 64 + srow; if (gr > M - 1) gr = M - 1;
            gload16(A + (size_t)gr * K + kc + scol, (char*)&lds[buf][s][0] + wbase);
        }
#pragma unroll
        for (int s = 0; s < 2; ++s) {
            int gr = n0 + s * 64 + srow; if (gr > N - 1) gr = N - 1;
            gload16(Bm + (size_t)gr * K + kc + scol, (char*)&lds[buf][4 + s][0] + wbase);
        }
    };
    auto LDA = [&](int buf, int mf) -> s16x8 {
        int row = wm * 128 + mf * 16 + lr;      // 0..255
        const char* b = (const char*)&lds[buf][row >> 6][0];
        int ir = row & 63;
        return *(const s16x8*)(b + ir * 64 + ((lg * 16) ^ (((ir >> 1) & 3) << 4)));
    };
    auto LDB = [&](int buf, int nf) -> s16x8 {
        int row = wn * 64 + nf * 16 + lr;       // 0..127
        const char* b = (const char*)&lds[buf][4 + (row >> 6)][0];
        int ir = row & 63;
        return *(const s16x8*)(b + ir * 64 + ((lg * 16) ^ (((ir >> 1) & 3) << 4)));
    };

    f32x4 acc[8][4];
#pragma unroll
    for (int i = 0; i < 8; ++i)
#pragma unroll
        for (int j = 0; j < 4; ++j) { f32x4 z = {0.f, 0.f, 0.f, 0.f}; acc[i][j] = z; }

    // prologue: stage t0,t1 (12 loads); wait t0 (t1's 6 in flight)
    STAGE(0, 0);
    STAGE(1, 1);
    VMC6;
    BAR();

    for (int t = 0; t < NTt; ++t) {
        const int cur = t & 1;
        s16x8 bf[4];
#pragma unroll
        for (int nf = 0; nf < 4; ++nf) bf[nf] = LDB(cur, nf);
#pragma unroll
        for (int mf = 0; mf < 8; ++mf) {
            s16x8 a = LDA(cur, mf);
#pragma unroll
            for (int nf = 0; nf < 4; ++nf)
                acc[mf][nf] = MFMA16(a, bf[nf], acc[mf][nf]);
        }
        BAR();                                   // all waves done with buf[cur]
        if (t + 2 < NTt) STAGE(cur, t + 2);      // refill freed buffer
        if (t + 1 < NTt) {
            if (t + 2 < NTt) { VMC6; } else { VMC0; }   // tile t+1 landed
        }
        BAR();
    }

    // ---- epilogue ----
    float biasv[4];
#pragma unroll
    for (int nf = 0; nf < 4; ++nf)
        biasv[nf] = bias[n0 + wn * 64 + nf * 16 + lr];

#pragma unroll
    for (int mf = 0; mf < 8; ++mf) {
#pragma unroll
        for (int r = 0; r < 4; ++r) {
            int row = m0 + wm * 128 + mf * 16 + lg * 4 + r;
            if (row >= M) continue;
            if (MODE == 0) {
                int bb = row / S_;
                int ss = row - bb * S_;
#pragma unroll
                for (int nf = 0; nf < 4; ++nf) {
                    int col = n0 + wn * 64 + nf * 16 + lr;
                    int hh = col >> 6, dd = col & 63;
                    float v = (acc[mf][nf][r] + biasv[nf]) * scl;
                    outB[(((size_t)bb * H_ + hh) * S_ + ss) * D_ + dd] = f2bf(v);
                }
            } else if (MODE == 1) {
                size_t base = (size_t)row * N;
#pragma unroll
                for (int nf = 0; nf < 4; ++nf) {
                    int col = n0 + wn * 64 + nf * 16 + lr;
                    outF[base + col] = acc[mf][nf][r] + biasv[nf] + res[base + col];
                }
            } else {
                size_t base = (size_t)row * N;
#pragma unroll
                for (int nf = 0; nf < 4; ++nf) {
                    int col = n0 + wn * 64 + nf * 16 + lr;
                    float x = acc[mf][nf][r] + biasv[nf];
                    float u2 = 1.5957691216057308f * (x + 0.044715f * x * x * x);
                    u2 = fminf(u2, 80.0f);
                    float tt = __expf(u2);          // gelu = x * t / (1 + t)
                    outB[base + col] = f2bf(x * tt / (1.0f + tt));
                }
            }
        }
    }
}

// ---------------- fused attention: one WG per (b,h) ----------------
__global__ __launch_bounds__(256)
void attn_kernel(const u16* __restrict__ qg_, const u16* __restrict__ kg_,
                 const u16* __restrict__ vg_, const u16* __restrict__ msum,
                 u16* __restrict__ ctx)
{
    __shared__ u16 Ks[272 * 72];
    __shared__ u16 Vt[64 * 296];
    __shared__ u16 Ps[4][16 * 32];
    const int bh = blockIdx.x;
    const int b = bh >> 4, hh = bh & 15;
    const u16* kg = kg_ + (size_t)bh * (S_ * D_);
    const u16* vg = vg_ + (size_t)bh * (S_ * D_);
    const u16* qg = qg_ + (size_t)bh * (S_ * D_);
    const int tid = threadIdx.x, lane = tid & 63, wv = tid >> 6;

    for (int c = tid; c < (S_ * D_) / 8; c += 256) {
        int s = c >> 3, d8 = (c & 7) << 3;
        s16x8 val = *(const s16x8*)(kg + s * 64 + d8);
        *(s16x8*)&Ks[s * 72 + d8] = val;
    }
    for (int idx = tid; idx < 15 * 64; idx += 256) {
        int rr = 257 + (idx >> 6), cc = idx & 63;
        Ks[rr * 72 + cc] = 0;
    }
    for (int c = tid; c < (S_ * D_) / 8; c += 256) {
        int s = c >> 3, d8 = (c & 7) << 3;
        s16x8 val = *(const s16x8*)(vg + s * 64 + d8);
#pragma unroll
        for (int j = 0; j < 8; ++j) Vt[(d8 + j) * 296 + s] = (u16)val[j];
    }
    for (int idx = tid; idx < 64 * 39; idx += 256) {
        int dd = idx / 39, cc = 257 + idx % 39;
        Vt[dd * 296 + cc] = 0;
    }
    __syncthreads();

    const int lr = lane & 15, lg = lane >> 4;
    for (int qb = wv; qb < 17; qb += 4) {
        const int q0 = qb * 16;
        int qrow = q0 + lr; if (qrow > S_ - 1) qrow = S_ - 1;
        s16x8 aq0 = *(const s16x8*)(qg + qrow * 64 + lg * 8);
        s16x8 aq1 = *(const s16x8*)(qg + qrow * 64 + 32 + lg * 8);

        f32x4 sc[17];
#pragma unroll
        for (int t = 0; t < 17; ++t) { f32x4 z = {0.f, 0.f, 0.f, 0.f}; sc[t] = z; }
#pragma unroll
        for (int t = 0; t < 17; ++t) {
            s16x8 b0 = *(const s16x8*)&Ks[(t * 16 + lr) * 72 + lg * 8];
            s16x8 b1 = *(const s16x8*)&Ks[(t * 16 + lr) * 72 + 32 + lg * 8];
            sc[t] = MFMA16(aq0, b0, sc[t]);
            sc[t] = MFMA16(aq1, b1, sc[t]);
        }
        float mx[4] = {-3e38f, -3e38f, -3e38f, -3e38f};
#pragma unroll
        for (int r = 0; r < 4; ++r) {
            int sq = q0 + lg * 4 + r; if (sq > S_ - 1) sq = S_ - 1;
            const u16* mrow = msum + ((size_t)b * S_ + sq) * 272;
#pragma unroll
            for (int t = 0; t < 17; ++t) {
                sc[t][r] += bf2f(mrow[t * 16 + lr]);
                mx[r] = fmaxf(mx[r], sc[t][r]);
            }
        }
#pragma unroll
        for (int r = 0; r < 4; ++r) {
#pragma unroll
            for (int xm = 1; xm <= 8; xm <<= 1)
                mx[r] = fmaxf(mx[r], __shfl_xor(mx[r], xm, 64));
        }
        float sum[4] = {0.f, 0.f, 0.f, 0.f};
#pragma unroll
        for (int t = 0; t < 17; ++t)
#pragma unroll
            for (int r = 0; r < 4; ++r) {
                float e = __expf(sc[t][r] - mx[r]);
                sc[t][r] = e; sum[r] += e;
            }
#pragma unroll
        for (int r = 0; r < 4; ++r) {
#pragma unroll
            for (int xm = 1; xm <= 8; xm <<= 1)
                sum[r] += __shfl_xor(sum[r], xm, 64);
        }

        f32x4 ac[4];
#pragma unroll
        for (int nt = 0; nt < 4; ++nt) { f32x4 z = {0.f, 0.f, 0.f, 0.f}; ac[nt] = z; }
        u16* myP = &Ps[wv][0];
#pragma unroll
        for (int kc = 0; kc < 9; ++kc) {
#pragma unroll
            for (int tt = 0; tt < 2; ++tt) {
                const int t = kc * 2 + tt;
#pragma unroll
                for (int r = 0; r < 4; ++r) {
                    float pv = (t < 17) ? sc[(t < 17) ? t : 0][r] : 0.f;
                    myP[(lg * 4 + r) * 32 + tt * 16 + lr] = f2bf(pv);
                }
            }
            s16x8 pa = *(const s16x8*)&myP[lr * 32 + lg * 8];
#pragma unroll
            for (int nt = 0; nt < 4; ++nt) {
                s16x8 bv = *(const s16x8*)&Vt[(nt * 16 + lr) * 296 + kc * 32 + lg * 8];
                ac[nt] = MFMA16(pa, bv, ac[nt]);
            }
        }
#pragma unroll
        for (int r = 0; r < 4; ++r) {
            int sq = q0 + lg * 4 + r;
            if (sq < S_) {
                float rd = 1.0f / sum[r];
                size_t base = (((size_t)b * S_ + sq) * H_ + hh) * D_;
#pragma unroll
                for (int nt = 0; nt < 4; ++nt)
                    ctx[base + nt * 16 + lr] = f2bf(ac[nt][r] * rd);
            }
        }
    }
}

// ---------------- launch ----------------
extern "C" void kernel_launch(void* const* d_in, const int* in_sizes, int n_in,
                              void* d_out, int out_size, void* d_ws, size_t ws_size,
                              hipStream_t stream)
{
    const float* hid   = (const float*)d_in[0];
    const float* am    = (const float*)d_in[1];
    const float* cm    = (const float*)d_in[2];
    const float* ln1w  = (const float*)d_in[3];
    const float* ln1b  = (const float*)d_in[4];
    const float* qw    = (const float*)d_in[5];
    const float* qbias = (const float*)d_in[6];
    const float* kw    = (const float*)d_in[7];
    const float* kbias = (const float*)d_in[8];
    const float* vw    = (const float*)d_in[9];
    const float* vbias = (const float*)d_in[10];
    const float* ow    = (const float*)d_in[11];
    const float* obias = (const float*)d_in[12];
    const float* ln2w  = (const float*)d_in[13];
    const float* ln2b  = (const float*)d_in[14];
    const float* f1w   = (const float*)d_in[15];
    const float* f1b   = (const float*)d_in[16];
    const float* f2w   = (const float*)d_in[17];
    const float* f2b   = (const float*)d_in[18];
    float* out = (float*)d_out;

    const size_t ME = (size_t)M_ * E_;
    u16* Wq   = (u16*)d_ws;
    u16* Wk   = Wq + 1048576;
    u16* Wv   = Wk + 1048576;
    u16* Wo   = Wv + 1048576;
    u16* Wf1  = Wo + 1048576;
    u16* Wf2  = Wf1 + 4 * 1048576;
    u16* xln  = Wf2 + 4 * 1048576;
    u16* qb_  = xln + ME;
    u16* kb_  = qb_ + ME;
    u16* vb_  = kb_ + ME;
    u16* ctx  = vb_ + ME;
    float* hbuf = (float*)(ctx + ME);
    u16* msum = (u16*)(hbuf + ME);
    u16* act  = qb_;      // reuse q..ctx region = M x I bf16 (exact fit)
    u16* x2   = xln;

    convert_w_kernel<<<3072, 256, 0, stream>>>(qw, kw, vw, ow, f1w, f2w, Wq);
    mask_combine_kernel<<<8736, 256, 0, stream>>>(am, cm, msum);
    ln_kernel<<<M_, 256, 0, stream>>>(hid, ln1w, ln1b, xln);
    gemmW<0><<<3 * MT_ * 8, 256, 0, stream>>>(xln, Wq, Wk, Wv, qbias, kbias, vbias,
                                              nullptr, nullptr, qb_, kb_, vb_,
                                              M_, 1024, 1024);
    attn_kernel<<<512, 256, 0, stream>>>(qb_, kb_, vb_, msum, ctx);
    gemmW<1><<<MT_ * 8, 256, 0, stream>>>(ctx, Wo, nullptr, nullptr, obias, nullptr, nullptr,
                                          hid, hbuf, nullptr, nullptr, nullptr,
                                          M_, 1024, 1024);
    ln_kernel<<<M_, 256, 0, stream>>>(hbuf, ln2w, ln2b, x2);
    gemmW<2><<<MT_ * 32, 256, 0, stream>>>(x2, Wf1, nullptr, nullptr, f1b, nullptr, nullptr,
                                           nullptr, nullptr, act, nullptr, nullptr,
                                           M_, 4096, 1024);
    gemmW<1><<<MT_ * 8, 256, 0, stream>>>(act, Wf2, nullptr, nullptr, f2b, nullptr, nullptr,
                                          hbuf, out, nullptr, nullptr, nullptr,
                                          M_, 1024, 4096);
}

// Round 10
// 425.002 us; speedup vs baseline: 3.8799x; 1.0060x over previous
//
#include <hip/hip_runtime.h>

typedef unsigned short u16;
typedef unsigned int   u32;
typedef short s16x8 __attribute__((ext_vector_type(8)));
typedef float f32x4 __attribute__((ext_vector_type(4)));

#define MFMA16(A,B,C) __builtin_amdgcn_mfma_f32_16x16x32_bf16((A),(B),(C),0,0,0)
#define BAR()  asm volatile("s_barrier" ::: "memory")
#define VMC6   asm volatile("s_waitcnt vmcnt(6)" ::: "memory")
#define VMC0   asm volatile("s_waitcnt vmcnt(0)" ::: "memory")

#define B_   32
#define S_   257
#define E_   1024
#define H_   16
#define D_   64
#define I_   4096
#define M_   (B_*S_)   // 8224
#define MT_  33        // ceil(M/256)

__device__ __forceinline__ u16 f2bf(float f) {
    u32 u = __float_as_uint(f);
    u32 r = u + 0x7fffu + ((u >> 16) & 1u);
    return (u16)(r >> 16);
}
__device__ __forceinline__ float bf2f(u16 b) {
    return __uint_as_float(((u32)b) << 16);
}

__device__ __forceinline__ void gload16(const void* g, void* l) {
    __builtin_amdgcn_global_load_lds(
        (const __attribute__((address_space(1))) u32*)g,
        (__attribute__((address_space(3))) u32*)l, 16, 0, 0);
}

// ---------------- weight fp32 -> bf16 convert (12M elems) ----------------
__global__ __launch_bounds__(256)
void convert_w_kernel(const float* __restrict__ qw, const float* __restrict__ kw,
                      const float* __restrict__ vw, const float* __restrict__ ow,
                      const float* __restrict__ f1, const float* __restrict__ f2,
                      u16* __restrict__ dst)
{
    const int total4 = (12 * 1048576) / 4;
    for (int i = blockIdx.x * 256 + threadIdx.x; i < total4; i += gridDim.x * 256) {
        int e = i * 4;
        int seg = e >> 20;
        const float* srcp; int off;
        if (seg < 4)      { srcp = (seg == 0 ? qw : seg == 1 ? kw : seg == 2 ? vw : ow); off = e & 1048575; }
        else if (seg < 8) { srcp = f1; off = e - 4 * 1048576; }
        else              { srcp = f2; off = e - 8 * 1048576; }
        float4 v = *(const float4*)(srcp + off);
        ushort4 o;
        o.x = f2bf(v.x); o.y = f2bf(v.y); o.z = f2bf(v.z); o.w = f2bf(v.w);
        *(ushort4*)(dst + e) = o;
    }
}

// ---------------- combined mask table: msum[b][sq][272] bf16 ----------------
__global__ __launch_bounds__(256)
void mask_combine_kernel(const float* __restrict__ am, const float* __restrict__ cm,
                         u16* __restrict__ msum)
{
    const int total = B_ * S_ * 272;
    for (int i = blockIdx.x * 256 + threadIdx.x; i < total; i += gridDim.x * 256) {
        int skv = i % 272;
        int rem = i / 272;
        int sq  = rem % S_;
        int b   = rem / S_;
        float v;
        if (skv < S_) {
            size_t o = ((size_t)b * S_ + sq) * S_ + skv;
            v = am[o] + cm[o];
        } else v = -1e30f;
        msum[i] = f2bf(v);
    }
}

// ---------------- LayerNorm row kernel ----------------
__global__ __launch_bounds__(256)
void ln_kernel(const float* __restrict__ src, const float* __restrict__ gam,
               const float* __restrict__ bet, u16* __restrict__ dst)
{
    int row = blockIdx.x;
    const float4* p = (const float4*)(src + (size_t)row * E_);
    float4 x = p[threadIdx.x];
    float s  = x.x + x.y + x.z + x.w;
    float s2 = x.x * x.x + x.y * x.y + x.z * x.z + x.w * x.w;
#pragma unroll
    for (int xm = 1; xm < 64; xm <<= 1) {
        s  += __shfl_xor(s,  xm, 64);
        s2 += __shfl_xor(s2, xm, 64);
    }
    __shared__ float red[8];
    int wv = threadIdx.x >> 6;
    if ((threadIdx.x & 63) == 0) { red[wv] = s; red[4 + wv] = s2; }
    __syncthreads();
    s  = red[0] + red[1] + red[2] + red[3];
    s2 = red[4] + red[5] + red[6] + red[7];
    float mu  = s * (1.0f / 1024.0f);
    float var = s2 * (1.0f / 1024.0f) - mu * mu;
    float rs  = rsqrtf(var + 1e-5f);
    float4 g  = ((const float4*)gam)[threadIdx.x];
    float4 be = ((const float4*)bet)[threadIdx.x];
    ushort4 o;
    o.x = f2bf((x.x - mu) * rs * g.x + be.x);
    o.y = f2bf((x.y - mu) * rs * g.y + be.y);
    o.z = f2bf((x.z - mu) * rs * g.z + be.z);
    o.w = f2bf((x.w - mu) * rs * g.w + be.w);
    ((ushort4*)dst)[(size_t)row * 256 + threadIdx.x] = o;
}

// ======== 256x128 NT GEMM, persistent multi-tile, BK=32, 48KB LDS ===========
// 4 waves x (128x64), 2 blocks/CU.  Desync loop, involution swizzle,
// 2-tile prefetch, counted vmcnt(6).  Strided tile loop: block handles
// tiles wg, wg+G, ... (FC1: 32 doubles, all dispatched in round 1 under
// the XCD swizzle -> makespan 3 rounds -> 2).
// MODE 0: QKV -> bf16 [B,H,S,D] (q scaled 1/8); MODE 1: f32 acc+bias+res;
// MODE 2: bf16 gelu(acc+bias)
template<int MODE>
__global__ __launch_bounds__(256, 2)
void gemmW(const u16* __restrict__ A,
           const u16* __restrict__ Bq, const u16* __restrict__ Bk, const u16* __restrict__ Bv,
           const float* __restrict__ biasq, const float* __restrict__ biask, const float* __restrict__ biasvv,
           const float* __restrict__ res, float* __restrict__ outF,
           u16* __restrict__ outBq, u16* __restrict__ outBk, u16* __restrict__ outBv,
           int M, int N, int K, int ntiles)
{
    __shared__ u16 lds[2][6][2048];   // 48 KB
    const int tid = threadIdx.x, lane = tid & 63, w = tid >> 6;
    const int lr = lane & 15, lg = lane >> 4;
    const int wm = w >> 1, wn = w & 1;          // 2 x 2 wave grid

    // --- bijective XCD chunk swizzle over flat grid ---
    const int G = gridDim.x;
    const int q8 = G >> 3, r8 = G & 7;
    const int xcd = blockIdx.x & 7, o8 = blockIdx.x >> 3;
    const int wg0 = (xcd < r8 ? xcd * (q8 + 1) : r8 * (q8 + 1) + (xcd - r8) * q8) + o8;

    const int NTL = N >> 7;                     // n-tiles per matrix
    const int NTt = K >> 5;                     // 32-K tiles

    // staging: phys byte p in 4KB segment -> logical l via involution
    const int p    = tid * 16;
    const int l_   = p ^ (((p >> 7) & 3) << 4);
    const int srow = l_ >> 6;
    const int scol = (l_ & 63) >> 1;
    const int wbase = w * 1024;

    for (int tile = wg0; tile < ntiles; tile += G) {
        int tw = tile;
        const u16* Bm = Bq; const float* bias = biasq; u16* outB = outBq;
        float scl = 1.0f;
        if (MODE == 0) {
            int mat = tw / (MT_ * NTL); tw -= mat * (MT_ * NTL);
            if (mat == 1)      { Bm = Bk; bias = biask; outB = outBk; }
            else if (mat == 2) { Bm = Bv; bias = biasvv; outB = outBv; }
            else               { Bm = Bq; bias = biasq; outB = outBq; }
            if (mat == 0) scl = 0.125f; else scl = 1.0f;
        }
        const int mt = tw / NTL, nt = tw - mt * NTL;   // nt fastest
        const int m0 = mt * 256, n0 = nt * 128;

        auto STAGE = [&](int buf, int t) {
            const int kc = t << 5;
#pragma unroll
            for (int s = 0; s < 4; ++s) {
                int gr = m0 + s * 64 + srow; if (gr > M - 1) gr = M - 1;
                gload16(A + (size_t)gr * K + kc + scol, (char*)&lds[buf][s][0] + wbase);
            }
#pragma unroll
            for (int s = 0; s < 2; ++s) {
                int gr = n0 + s * 64 + srow; if (gr > N - 1) gr = N - 1;
                gload16(Bm + (size_t)gr * K + kc + scol, (char*)&lds[buf][4 + s][0] + wbase);
            }
        };
        auto LDA = [&](int buf, int mf) -> s16x8 {
            int row = wm * 128 + mf * 16 + lr;
            const char* b = (const char*)&lds[buf][row >> 6][0];
            int ir = row & 63;
            return *(const s16x8*)(b + ir * 64 + ((lg * 16) ^ (((ir >> 1) & 3) << 4)));
        };
        auto LDB = [&](int buf, int nf) -> s16x8 {
            int row = wn * 64 + nf * 16 + lr;
            const char* b = (const char*)&lds[buf][4 + (row >> 6)][0];
            int ir = row & 63;
            return *(const s16x8*)(b + ir * 64 + ((lg * 16) ^ (((ir >> 1) & 3) << 4)));
        };

        f32x4 acc[8][4];
#pragma unroll
        for (int i = 0; i < 8; ++i)
#pragma unroll
            for (int j = 0; j < 4; ++j) { f32x4 z = {0.f, 0.f, 0.f, 0.f}; acc[i][j] = z; }

        STAGE(0, 0);
        STAGE(1, 1);
        VMC6;
        BAR();

        for (int t = 0; t < NTt; ++t) {
            const int cur = t & 1;
            s16x8 bf[4];
#pragma unroll
            for (int nf = 0; nf < 4; ++nf) bf[nf] = LDB(cur, nf);
#pragma unroll
            for (int mf = 0; mf < 8; ++mf) {
                s16x8 a = LDA(cur, mf);
#pragma unroll
                for (int nf = 0; nf < 4; ++nf)
                    acc[mf][nf] = MFMA16(a, bf[nf], acc[mf][nf]);
            }
            BAR();
            if (t + 2 < NTt) STAGE(cur, t + 2);
            if (t + 1 < NTt) {
                if (t + 2 < NTt) { VMC6; } else { VMC0; }
            }
            BAR();
        }

        float biasv[4];
#pragma unroll
        for (int nf = 0; nf < 4; ++nf)
            biasv[nf] = bias[n0 + wn * 64 + nf * 16 + lr];

#pragma unroll
        for (int mf = 0; mf < 8; ++mf) {
#pragma unroll
            for (int r = 0; r < 4; ++r) {
                int row = m0 + wm * 128 + mf * 16 + lg * 4 + r;
                if (row >= M) continue;
                if (MODE == 0) {
                    int bb = row / S_;
                    int ss = row - bb * S_;
#pragma unroll
                    for (int nf = 0; nf < 4; ++nf) {
                        int col = n0 + wn * 64 + nf * 16 + lr;
                        int hh = col >> 6, dd = col & 63;
                        float v = (acc[mf][nf][r] + biasv[nf]) * scl;
                        outB[(((size_t)bb * H_ + hh) * S_ + ss) * D_ + dd] = f2bf(v);
                    }
                } else if (MODE == 1) {
                    size_t base = (size_t)row * N;
#pragma unroll
                    for (int nf = 0; nf < 4; ++nf) {
                        int col = n0 + wn * 64 + nf * 16 + lr;
                        outF[base + col] = acc[mf][nf][r] + biasv[nf] + res[base + col];
                    }
                } else {
                    size_t base = (size_t)row * N;
#pragma unroll
                    for (int nf = 0; nf < 4; ++nf) {
                        int col = n0 + wn * 64 + nf * 16 + lr;
                        float x = acc[mf][nf][r] + biasv[nf];
                        float u2 = 1.5957691216057308f * (x + 0.044715f * x * x * x);
                        u2 = fminf(u2, 80.0f);
                        float tt = __expf(u2);          // gelu = x * t / (1 + t)
                        outB[base + col] = f2bf(x * tt / (1.0f + tt));
                    }
                }
            }
        }
        if (tile + G < ntiles) BAR();   // LDS safe: next tile's STAGE after all reads
    }
}

// ---------------- fused attention: one WG per (b,h), 2 blocks/CU ------------
// Ks [272][72]: K data in cols 0..63; cols 64..71 of rows 0..255 host the
// per-wave P staging (wave wv owns rows wv*64..wv*64+63).  LDS total 77056 B.
__global__ __launch_bounds__(256, 2)
void attn_kernel(const u16* __restrict__ qg_, const u16* __restrict__ kg_,
                 const u16* __restrict__ vg_, const u16* __restrict__ msum,
                 u16* __restrict__ ctx)
{
    __shared__ u16 Ks[272 * 72];     // 39168 B
    __shared__ u16 Vt[64 * 296];     // 37888 B   (total 77056 -> 2 WG/CU)
    const int bh = blockIdx.x;
    const int b = bh >> 4, hh = bh & 15;
    const u16* kg = kg_ + (size_t)bh * (S_ * D_);
    const u16* vg = vg_ + (size_t)bh * (S_ * D_);
    const u16* qg = qg_ + (size_t)bh * (S_ * D_);
    const int tid = threadIdx.x, lane = tid & 63, wv = tid >> 6;

    for (int c = tid; c < (S_ * D_) / 8; c += 256) {
        int s = c >> 3, d8 = (c & 7) << 3;
        s16x8 val = *(const s16x8*)(kg + s * 64 + d8);
        *(s16x8*)&Ks[s * 72 + d8] = val;
    }
    for (int idx = tid; idx < 15 * 64; idx += 256) {
        int rr = 257 + (idx >> 6), cc = idx & 63;
        Ks[rr * 72 + cc] = 0;
    }
    for (int c = tid; c < (S_ * D_) / 8; c += 256) {
        int s = c >> 3, d8 = (c & 7) << 3;
        s16x8 val = *(const s16x8*)(vg + s * 64 + d8);
#pragma unroll
        for (int j = 0; j < 8; ++j) Vt[(d8 + j) * 296 + s] = (u16)val[j];
    }
    for (int idx = tid; idx < 64 * 39; idx += 256) {
        int dd = idx / 39, cc = 257 + idx % 39;
        Vt[dd * 296 + cc] = 0;
    }
    __syncthreads();

    const int lr = lane & 15, lg = lane >> 4;
    for (int qb = wv; qb < 17; qb += 4) {
        const int q0 = qb * 16;
        int qrow = q0 + lr; if (qrow > S_ - 1) qrow = S_ - 1;
        s16x8 aq0 = *(const s16x8*)(qg + qrow * 64 + lg * 8);
        s16x8 aq1 = *(const s16x8*)(qg + qrow * 64 + 32 + lg * 8);

        f32x4 sc[17];
#pragma unroll
        for (int t = 0; t < 17; ++t) { f32x4 z = {0.f, 0.f, 0.f, 0.f}; sc[t] = z; }
#pragma unroll
        for (int t = 0; t < 17; ++t) {
            s16x8 b0 = *(const s16x8*)&Ks[(t * 16 + lr) * 72 + lg * 8];
            s16x8 b1 = *(const s16x8*)&Ks[(t * 16 + lr) * 72 + 32 + lg * 8];
            sc[t] = MFMA16(aq0, b0, sc[t]);
            sc[t] = MFMA16(aq1, b1, sc[t]);
        }
        float mx[4] = {-3e38f, -3e38f, -3e38f, -3e38f};
#pragma unroll
        for (int r = 0; r < 4; ++r) {
            int sq = q0 + lg * 4 + r; if (sq > S_ - 1) sq = S_ - 1;
            const u16* mrow = msum + ((size_t)b * S_ + sq) * 272;
#pragma unroll
            for (int t = 0; t < 17; ++t) {
                sc[t][r] += bf2f(mrow[t * 16 + lr]);
                mx[r] = fmaxf(mx[r], sc[t][r]);
            }
        }
#pragma unroll
        for (int r = 0; r < 4; ++r) {
#pragma unroll
            for (int xm = 1; xm <= 8; xm <<= 1)
                mx[r] = fmaxf(mx[r], __shfl_xor(mx[r], xm, 64));
        }
        float sum[4] = {0.f, 0.f, 0.f, 0.f};
#pragma unroll
        for (int t = 0; t < 17; ++t)
#pragma unroll
            for (int r = 0; r < 4; ++r) {
                float e = __expf(sc[t][r] - mx[r]);
                sc[t][r] = e; sum[r] += e;
            }
#pragma unroll
        for (int r = 0; r < 4; ++r) {
#pragma unroll
            for (int xm = 1; xm <= 8; xm <<= 1)
                sum[r] += __shfl_xor(sum[r], xm, 64);
        }

        f32x4 ac[4];
#pragma unroll
        for (int nt = 0; nt < 4; ++nt) { f32x4 z = {0.f, 0.f, 0.f, 0.f}; ac[nt] = z; }
        // P staging inside Ks padding: wave wv owns rows wv*64..+63, cols 64..71
        u16* pbase = &Ks[(size_t)wv * 64 * 72];
#pragma unroll
        for (int kc = 0; kc < 9; ++kc) {
#pragma unroll
            for (int tt = 0; tt < 2; ++tt) {
                const int t = kc * 2 + tt;
#pragma unroll
                for (int r = 0; r < 4; ++r) {
                    float pv = (t < 17) ? sc[(t < 17) ? t : 0][r] : 0.f;
                    int pr = lg * 4 + r, pc = tt * 16 + lr;
                    pbase[(pr * 4 + (pc >> 3)) * 72 + 64 + (pc & 7)] = f2bf(pv);
                }
            }
            s16x8 pa = *(const s16x8*)&pbase[(lr * 4 + lg) * 72 + 64];
#pragma unroll
            for (int nt = 0; nt < 4; ++nt) {
                s16x8 bv = *(const s16x8*)&Vt[(nt * 16 + lr) * 296 + kc * 32 + lg * 8];
                ac[nt] = MFMA16(pa, bv, ac[nt]);
            }
        }
#pragma unroll
        for (int r = 0; r < 4; ++r) {
            int sq = q0 + lg * 4 + r;
            if (sq < S_) {
                float rd = 1.0f / sum[r];
                size_t base = (((size_t)b * S_ + sq) * H_ + hh) * D_;
#pragma unroll
                for (int nt = 0; nt < 4; ++nt)
                    ctx[base + nt * 16 + lr] = f2bf(ac[nt][r] * rd);
            }
        }
    }
}

// ---------------- launch ----------------
extern "C" void kernel_launch(void* const* d_in, const int* in_sizes, int n_in,
                              void* d_out, int out_size, void* d_ws, size_t ws_size,
                              hipStream_t stream)
{
    const float* hid   = (const float*)d_in[0];
    const float* am    = (const float*)d_in[1];
    const float* cm    = (const float*)d_in[2];
    const float* ln1w  = (const float*)d_in[3];
    const float* ln1b  = (const float*)d_in[4];
    const float* qw    = (const float*)d_in[5];
    const float* qbias = (const float*)d_in[6];
    const float* kw    = (const float*)d_in[7];
    const float* kbias = (const float*)d_in[8];
    const float* vw    = (const float*)d_in[9];
    const float* vbias = (const float*)d_in[10];
    const float* ow    = (const float*)d_in[11];
    const float* obias = (const float*)d_in[12];
    const float* ln2w  = (const float*)d_in[13];
    const float* ln2b  = (const float*)d_in[14];
    const float* f1w   = (const float*)d_in[15];
    const float* f1b   = (const float*)d_in[16];
    const float* f2w   = (const float*)d_in[17];
    const float* f2b   = (const float*)d_in[18];
    float* out = (float*)d_out;

    const size_t ME = (size_t)M_ * E_;
    u16* Wq   = (u16*)d_ws;
    u16* Wk   = Wq + 1048576;
    u16* Wv   = Wk + 1048576;
    u16* Wo   = Wv + 1048576;
    u16* Wf1  = Wo + 1048576;
    u16* Wf2  = Wf1 + 4 * 1048576;
    u16* xln  = Wf2 + 4 * 1048576;
    u16* qb_  = xln + ME;
    u16* kb_  = qb_ + ME;
    u16* vb_  = kb_ + ME;
    u16* ctx  = vb_ + ME;
    float* hbuf = (float*)(ctx + ME);
    u16* msum = (u16*)(hbuf + ME);
    u16* act  = qb_;      // reuse q..ctx region = M x I bf16 (exact fit)
    u16* x2   = xln;

    convert_w_kernel<<<3072, 256, 0, stream>>>(qw, kw, vw, ow, f1w, f2w, Wq);
    mask_combine_kernel<<<8736, 256, 0, stream>>>(am, cm, msum);
    ln_kernel<<<M_, 256, 0, stream>>>(hid, ln1w, ln1b, xln);
    // QKV: 3 * 33 * 8 = 792 tiles, grid 792 (no doubles)
    gemmW<0><<<792, 256, 0, stream>>>(xln, Wq, Wk, Wv, qbias, kbias, vbias,
                                      nullptr, nullptr, qb_, kb_, vb_,
                                      M_, 1024, 1024, 792);
    attn_kernel<<<512, 256, 0, stream>>>(qb_, kb_, vb_, msum, ctx);
    // O-proj: 264 tiles, grid 264
    gemmW<1><<<264, 256, 0, stream>>>(ctx, Wo, nullptr, nullptr, obias, nullptr, nullptr,
                                      hid, hbuf, nullptr, nullptr, nullptr,
                                      M_, 1024, 1024, 264);
    ln_kernel<<<M_, 256, 0, stream>>>(hbuf, ln2w, ln2b, x2);
    // FC1: 33*32 = 1056 tiles, grid 1024 -> 32 doubles (round-1 under swizzle)
    gemmW<2><<<1024, 256, 0, stream>>>(x2, Wf1, nullptr, nullptr, f1b, nullptr, nullptr,
                                       nullptr, nullptr, act, nullptr, nullptr,
                                       M_, 4096, 1024, 1056);
    // FC2: 264 tiles, grid 264
    gemmW<1><<<264, 256, 0, stream>>>(act, Wf2, nullptr, nullptr, f2b, nullptr, nullptr,
                                      hbuf, out, nullptr, nullptr, nullptr,
                                      M_, 1024, 4096, 264);
}